// Round 4
// baseline (664.197 us; speedup 1.0000x reference)
//
#include <hip/hip_runtime.h>
#include <stdint.h>

// Problem dims (fixed)
#define B_  4
#define L_  4096
#define D_  1024
#define H_  16
#define DH  64
#define M_  (B_*L_)   // 16384 rows

typedef _Float16 f16;
typedef __attribute__((ext_vector_type(8))) _Float16 f16x8;
typedef __attribute__((ext_vector_type(4))) _Float16 f16x4;
typedef __attribute__((ext_vector_type(4))) float    f32x4;

// ---------------- async global->LDS (16B per lane) ----------------
__device__ __forceinline__ void cp16(const void* g, void* l) {
  __builtin_amdgcn_global_load_lds(
      (const __attribute__((address_space(1))) void*)g,
      (__attribute__((address_space(3))) void*)l,
      16, 0, 0);
}

#define MFMA(a,b,c) __builtin_amdgcn_mfma_f32_16x16x32_f16(a,b,c,0,0,0)

// 8-phase sync primitives (T3+T4+T5).
#define PH_IN do { __builtin_amdgcn_s_barrier(); \
  asm volatile("s_waitcnt lgkmcnt(0)" ::: "memory"); \
  __builtin_amdgcn_sched_barrier(0); \
  __builtin_amdgcn_s_setprio(1); } while (0)
#define PH_OUT do { __builtin_amdgcn_s_setprio(0); \
  __builtin_amdgcn_sched_barrier(0); \
  asm volatile("" ::: "memory"); \
  __builtin_amdgcn_s_barrier(); } while (0)
#define VMW(nimm) asm volatile("s_waitcnt vmcnt(" #nimm ")" ::: "memory")

// ---------------- fp32 -> fp16 cast (weights hi only) ----------------
__global__ __launch_bounds__(256) void k_cvt2(const float* __restrict__ x0,
                                              f16* __restrict__ y0,
                                              const float* __restrict__ x1,
                                              f16* __restrict__ y1, int n8each) {
  int i = blockIdx.x * 256 + threadIdx.x;
  const float* x = x0; f16* y = y0;
  if (i >= n8each) { x = x1; y = y1; i -= n8each; }
  const float4* xv = (const float4*)x;
  float4 a = xv[2*i], b = xv[2*i+1];
  f16x8 o;
  o[0]=(f16)a.x; o[1]=(f16)a.y; o[2]=(f16)a.z; o[3]=(f16)a.w;
  o[4]=(f16)b.x; o[5]=(f16)b.y; o[6]=(f16)b.z; o[7]=(f16)b.w;
  ((f16x8*)y)[i] = o;
}

// ---------------- fp32 weight -> interleaved [hi;lo] catalog -------------
// W row n: hi -> cat row 32*(n>>4)+(n&15), lo -> +16.
__device__ __forceinline__ void split_one(const float* __restrict__ x,
                                          f16* __restrict__ cat, int i) {
  float4 a = ((const float4*)x)[i];
  int n  = i >> 8;
  int k4 = i & 255;
  f16 h0=(f16)a.x, h1=(f16)a.y, h2=(f16)a.z, h3=(f16)a.w;
  f16x4 hv = {h0, h1, h2, h3};
  f16x4 lv = {(f16)(a.x-(float)h0), (f16)(a.y-(float)h1),
              (f16)(a.z-(float)h2), (f16)(a.w-(float)h3)};
  size_t rh = (size_t)((n >> 4) * 32 + (n & 15));
  ((f16x4*)cat)[rh * 256 + k4]        = hv;
  ((f16x4*)cat)[(rh + 16) * 256 + k4] = lv;
}

__global__ __launch_bounds__(256) void k_split2(const float* __restrict__ x0,
                                                f16* __restrict__ c0,
                                                const float* __restrict__ x1,
                                                f16* __restrict__ c1, int n4each) {
  int i = blockIdx.x * 256 + threadIdx.x;
  if (i < n4each) split_one(x0, c0, i);
  else            split_one(x1, c1, i - n4each);
}

// ---------------- 256x256 8-phase GEMM, fp32 A (fused cvt) -----------------
// 512 thr = 8 waves (2M x 4N); wave tile 128x64; BK=64, dbuf 128KB LDS,
// swizzle blk^=(row&7) on 16B chunks. A is fp32 in global: staged via
// reg (4x global_load_dwordx4 issued 2 phases early) -> v_cvt -> swizzled
// ds_write_b128 (T14 issue-early/write-late). B stays global_load_lds with
// pre-swizzled source. vmcnt ledger (per wave, in-order counting):
//   ops/iter: p1 A(4) p2 A(4) p3 B(2) p4 B(2) p5 A(4) p6 A(4) p7 B(2) p8 B(2)
//   waits: p3 vmcnt(6|4-last) ensures p1-A done; p4 vmcnt(4|0-last) -> p2-A;
//          p7 vmcnt(6) -> p5-A (+B3,B4 done << next p1); p8 vmcnt(4) -> p6-A.
//   ds_write publish: each phase's PH_IN lgkmcnt(0) drains own writes before
//   the next barrier; readers are >=2 barriers later.
// mode 1: bias+sigmoid+l2norm(64-col head)+opt mask -> f16 (N=1024)
// mode 2: fold hi/lo pairs + bias -> f16   (N=2048 interleaved -> 1024)
// mode 3: fold hi/lo pairs + bias -> fp32  (N=2048 interleaved -> 1024)
struct GemmJob {
  const float* A; const f16* Bw; const float* bias; const float* mask;
  float* Cf; f16* Ch; int mode; int N;
};

__global__ __launch_bounds__(512, 1) void k_gemm8(GemmJob j0, GemmJob j1,
                                                  int nblk0, int M, int K) {
  __shared__ __align__(16) char smem[135168];
  char* sA = smem;
  char* sB = smem + 65536;
  const int t = threadIdx.x;

  int raw = (int)blockIdx.x;
  GemmJob J; int bid, nblk;
  if (raw < nblk0) { J = j0; bid = raw;         nblk = nblk0; }
  else             { J = j1; bid = raw - nblk0; nblk = (int)gridDim.x - nblk0; }
  const int N = J.N;
  const int nbn = N >> 8;
  { // XCD-aware swizzle within job (job sizes are multiples of 8)
    int cpx = nblk >> 3;
    bid = (bid & 7) * cpx + (bid >> 3);
  }
  const int bm = (bid / nbn) << 8;
  const int bn = (bid % nbn) << 8;
  const int lane = t & 63, wave = t >> 6;
  const int wm = wave >> 2;        // 0..1 : rows [wm*128, +128)
  const int wn = wave & 3;         // 0..3 : cols [wn*64, +64)
  const int fm = lane & 15, fkb = lane >> 4;

  const float* Af = J.A;
  const f16*   Bb = J.Bw;

// issue 4x dwordx4 fp32 A loads for one 128x64 half-tile (16 f16/thread)
#define AISS(RR, HALF, T_) do { \
  _Pragma("unroll") for (int q = 0; q < 2; ++q) { \
    int li = (q << 9) + t; int row = li >> 3, cb = li & 7; \
    const float* gp = Af + (size_t)(bm + ((HALF) << 7) + row) * K \
                         + ((T_) << 6) + (cb << 3); \
    RR[2*q]   = *(const float4*)gp; \
    RR[2*q+1] = *(const float4*)(gp + 4); \
  } } while (0)

// cvt + swizzled ds_write of the half-tile into buf
#define ACVT(RR, HALF, BUF) do { \
  _Pragma("unroll") for (int q = 0; q < 2; ++q) { \
    int li = (q << 9) + t; int row = li >> 3, cb = li & 7; \
    f16x8 o; \
    o[0]=(f16)RR[2*q].x;   o[1]=(f16)RR[2*q].y;   o[2]=(f16)RR[2*q].z;   o[3]=(f16)RR[2*q].w; \
    o[4]=(f16)RR[2*q+1].x; o[5]=(f16)RR[2*q+1].y; o[6]=(f16)RR[2*q+1].z; o[7]=(f16)RR[2*q+1].w; \
    *(f16x8*)(sA + (BUF) * 32768 + (HALF) * 16384 \
              + (((row << 3) + (cb ^ (row & 7))) << 4)) = o; \
  } } while (0)

  auto SB_ = [&](int T, int buf, int half) {
#pragma unroll
    for (int q = 0; q < 2; ++q) {
      int li = (q << 9) + t;
      int row = li >> 3, cb = li & 7;
      const f16* g = Bb + (size_t)(bn + (half << 7) + row) * K
                        + (T << 6) + ((cb ^ (row & 7)) << 3);
      cp16(g, sB + buf * 32768 + half * 16384 + li * 16);
    }
  };
  auto LDA = [&](int buf, int i, int ks) -> f16x8 {
    int row = (i << 4) + fm;
    int blk = ((ks << 2) + fkb) ^ (row & 7);
    return *(const f16x8*)(sA + buf * 32768 + (wm << 14) + (row << 7) + (blk << 4));
  };
  auto LDB = [&](int buf, int j, int ks) -> f16x8 {
    int row = ((wn & 1) << 6) + (j << 4) + fm;
    int blk = ((ks << 2) + fkb) ^ (row & 7);
    return *(const f16x8*)(sB + buf * 32768 + ((wn >> 1) << 14) + (row << 7) + (blk << 4));
  };

  f32x4 acc[8][4] = {};
  float4 rA0[4], rA1[4];

  // ---- prologue: A(0) via reg-cvt; B(0),B(1) via gload_lds
  AISS(rA0, 0, 0); AISS(rA1, 1, 0);      // 8 vm ops
  SB_(0, 0, 0); SB_(0, 0, 1);             // 4
  SB_(1, 1, 0); SB_(1, 1, 1);             // 4
  VMW(12); ACVT(rA0, 0, 0);
  VMW(8);  ACVT(rA1, 1, 0);
  VMW(4);                                  // B(0) landed; B(1) in flight
  asm volatile("s_waitcnt lgkmcnt(0)" ::: "memory");
  __builtin_amdgcn_s_barrier();

  const int NI = K >> 7;
  for (int it = 0; it < NI; ++it) {
    const bool nl = (it != NI - 1);
    const int t2 = 2 * it + 2, t3 = 2 * it + 3;
    f16x8 aL[4][2], aH[4][2], bA[2][2], bB[2][2];

    // p1 (buf0): read aL,bA; issue A(2it+1) h0 loads
#pragma unroll
    for (int i = 0; i < 4; ++i) { aL[i][0] = LDA(0,i,0); aL[i][1] = LDA(0,i,1); }
#pragma unroll
    for (int j = 0; j < 2; ++j) { bA[j][0] = LDB(0,j,0); bA[j][1] = LDB(0,j,1); }
    AISS(rA0, 0, 2*it+1);
    PH_IN;
#pragma unroll
    for (int i = 0; i < 4; ++i)
#pragma unroll
      for (int j = 0; j < 2; ++j) {
        acc[i][j] = MFMA(aL[i][0], bA[j][0], acc[i][j]);
        acc[i][j] = MFMA(aL[i][1], bA[j][1], acc[i][j]);
      }
    PH_OUT;
    // p2: read bB; issue A(2it+1) h1 loads
#pragma unroll
    for (int j = 0; j < 2; ++j) { bB[j][0] = LDB(0,j+2,0); bB[j][1] = LDB(0,j+2,1); }
    AISS(rA1, 1, 2*it+1);
    PH_IN;
#pragma unroll
    for (int i = 0; i < 4; ++i)
#pragma unroll
      for (int j = 0; j < 2; ++j) {
        acc[i][j+2] = MFMA(aL[i][0], bB[j][0], acc[i][j+2]);
        acc[i][j+2] = MFMA(aL[i][1], bB[j][1], acc[i][j+2]);
      }
    PH_OUT;
    // p3: read aH; stage b0.B h0; cvt+write A(2it+1) h0 -> buf1
#pragma unroll
    for (int i = 0; i < 4; ++i) { aH[i][0] = LDA(0,i+4,0); aH[i][1] = LDA(0,i+4,1); }
    if (nl) { SB_(t2, 0, 0); VMW(6); } else { VMW(4); }
    ACVT(rA0, 0, 1);
    PH_IN;
#pragma unroll
    for (int i = 0; i < 4; ++i)
#pragma unroll
      for (int j = 0; j < 2; ++j) {
        acc[i+4][j] = MFMA(aH[i][0], bA[j][0], acc[i+4][j]);
        acc[i+4][j] = MFMA(aH[i][1], bA[j][1], acc[i+4][j]);
      }
    PH_OUT;
    // p4: stage b0.B h1; cvt+write A(2it+1) h1 -> buf1
    if (nl) { SB_(t2, 0, 1); VMW(4); } else { VMW(0); }
    ACVT(rA1, 1, 1);
    PH_IN;
#pragma unroll
    for (int i = 0; i < 4; ++i)
#pragma unroll
      for (int j = 0; j < 2; ++j) {
        acc[i+4][j+2] = MFMA(aH[i][0], bB[j][0], acc[i+4][j+2]);
        acc[i+4][j+2] = MFMA(aH[i][1], bB[j][1], acc[i+4][j+2]);
      }
    PH_OUT;
    // p5 (buf1): read aL,bA; issue A(t2) h0 loads
#pragma unroll
    for (int i = 0; i < 4; ++i) { aL[i][0] = LDA(1,i,0); aL[i][1] = LDA(1,i,1); }
#pragma unroll
    for (int j = 0; j < 2; ++j) { bA[j][0] = LDB(1,j,0); bA[j][1] = LDB(1,j,1); }
    if (nl) AISS(rA0, 0, t2);
    PH_IN;
#pragma unroll
    for (int i = 0; i < 4; ++i)
#pragma unroll
      for (int j = 0; j < 2; ++j) {
        acc[i][j] = MFMA(aL[i][0], bA[j][0], acc[i][j]);
        acc[i][j] = MFMA(aL[i][1], bA[j][1], acc[i][j]);
      }
    PH_OUT;
    // p6: read bB; issue A(t2) h1 loads
#pragma unroll
    for (int j = 0; j < 2; ++j) { bB[j][0] = LDB(1,j+2,0); bB[j][1] = LDB(1,j+2,1); }
    if (nl) AISS(rA1, 1, t2);
    PH_IN;
#pragma unroll
    for (int i = 0; i < 4; ++i)
#pragma unroll
      for (int j = 0; j < 2; ++j) {
        acc[i][j+2] = MFMA(aL[i][0], bB[j][0], acc[i][j+2]);
        acc[i][j+2] = MFMA(aL[i][1], bB[j][1], acc[i][j+2]);
      }
    PH_OUT;
    // p7: read aH; stage b1.B h0; cvt+write A(t2) h0 -> buf0
#pragma unroll
    for (int i = 0; i < 4; ++i) { aH[i][0] = LDA(1,i+4,0); aH[i][1] = LDA(1,i+4,1); }
    if (nl) { SB_(t3, 1, 0); VMW(6); ACVT(rA0, 0, 0); }
    PH_IN;
#pragma unroll
    for (int i = 0; i < 4; ++i)
#pragma unroll
      for (int j = 0; j < 2; ++j) {
        acc[i+4][j] = MFMA(aH[i][0], bA[j][0], acc[i+4][j]);
        acc[i+4][j] = MFMA(aH[i][1], bA[j][1], acc[i+4][j]);
      }
    PH_OUT;
    // p8: stage b1.B h1; cvt+write A(t2) h1 -> buf0
    if (nl) { SB_(t3, 1, 1); VMW(4); ACVT(rA1, 1, 0); }
    PH_IN;
#pragma unroll
    for (int i = 0; i < 4; ++i)
#pragma unroll
      for (int j = 0; j < 2; ++j) {
        acc[i+4][j+2] = MFMA(aH[i][0], bB[j][0], acc[i+4][j+2]);
        acc[i+4][j+2] = MFMA(aH[i][1], bB[j][1], acc[i+4][j+2]);
      }
    PH_OUT;
  }

  // ---------------- epilogue (LDS-coalesced stores) ----------------
  // C/D layout: col = lane&15, row = (lane>>4)*4 + reg  [m89/m91]
  const int cr = (lane >> 4) << 2, ccol = lane & 15;
  float* sOut = (float*)smem;
  if (J.mode == 1) {
    // Stage RAW acc+bias fp32 into sOut[128][260] per 128-row half; all
    // sigmoid/l2norm math happens on readback with all 512 threads.
    float bvj[4];
#pragma unroll
    for (int j = 0; j < 4; ++j) bvj[j] = J.bias[bn + wn*64 + j*16 + ccol];
    const int rbr = t >> 6;            // readback row-within-group (wave id)
    const int c4  = (t & 63) * 4;      // readback col (4 f32)
    for (int h = 0; h < 2; ++h) {
      if (wm == h) {
#pragma unroll
        for (int i = 0; i < 8; ++i)
#pragma unroll
          for (int r = 0; r < 4; ++r) {
            int rl = i*16 + cr + r;    // 0..127 within this half
#pragma unroll
            for (int j = 0; j < 4; ++j)
              sOut[rl*260 + wn*64 + j*16 + ccol] = acc[i][j][r] + bvj[j];
          }
      }
      __syncthreads();
      // readback: per row, lanes 0-15/16-31/32-47/48-63 each own one 64-col
      // head; 4-deep shfl_xor over the 16-lane group gives the head's sum.
#pragma unroll
      for (int sp = 0; sp < 16; ++sp) {
        int rr = sp*8 + rbr;
        int gm = bm + h*128 + rr;
        f32x4 v = *(const f32x4*)&sOut[rr*260 + c4];
        float s0 = 1.0f / (1.0f + __expf(-v[0]));
        float s1 = 1.0f / (1.0f + __expf(-v[1]));
        float s2 = 1.0f / (1.0f + __expf(-v[2]));
        float s3 = 1.0f / (1.0f + __expf(-v[3]));
        float ss = s0*s0 + s1*s1 + s2*s2 + s3*s3;
        ss += __shfl_xor(ss, 1, 64);
        ss += __shfl_xor(ss, 2, 64);
        ss += __shfl_xor(ss, 4, 64);
        ss += __shfl_xor(ss, 8, 64);
        float sc = 1.0f / fmaxf(sqrtf(ss), 1e-12f);
        if (J.mask) sc *= J.mask[gm];
        f16x4 o = {(f16)(s0*sc), (f16)(s1*sc), (f16)(s2*sc), (f16)(s3*sc)};
        *(f16x4*)&J.Ch[(size_t)gm * N + bn + c4] = o;
      }
      __syncthreads();
    }
  } else {
    // fold hi/lo, stage into sOut[256][132] (pitch 132: +4 rows -> +16 banks)
#pragma unroll
    for (int j2 = 0; j2 < 2; ++j2) {
      int ocl = wn*32 + j2*16 + ccol;       // 0..127 block-local real col
      float bv = J.bias[(bn >> 1) + ocl];
#pragma unroll
      for (int i = 0; i < 8; ++i)
#pragma unroll
        for (int r = 0; r < 4; ++r) {
          int rl = wm*128 + i*16 + cr + r;  // 0..255
          sOut[rl*132 + ocl] = acc[i][2*j2][r] + acc[i][2*j2+1][r] + bv;
        }
    }
    __syncthreads();
    const int No = N >> 1;                  // 1024
#pragma unroll
    for (int sp = 0; sp < 16; ++sp) {
      int rl = sp*16 + (t >> 5);
      int c4 = (t & 31) * 4;
      f32x4 v = *(const f32x4*)&sOut[rl*132 + c4];
      size_t g = (size_t)(bm + rl) * No + (bn >> 1) + c4;
      if (J.mode == 2) {
        f16x4 o = {(f16)v[0], (f16)v[1], (f16)v[2], (f16)v[3]};
        *(f16x4*)&J.Ch[g] = o;
      } else {
        *(f32x4*)&J.Cf[g] = v;
      }
    }
  }
#undef AISS
#undef ACVT
}

// ---------------- kv via MFMA: per (head, chunk of 512 rows) ---------------
#define SKT 72
__global__ __launch_bounds__(256) void k_kv_mfma(const f16* __restrict__ Kh,
                                                 const f16* __restrict__ Vh,
                                                 float* __restrict__ part) {
  __shared__ __align__(16) f16 sKt[64 * SKT];    // [d][l]
  __shared__ __align__(16) f16 sVt[128 * SKT];   // [c2][l]
  int head = blockIdx.x >> 3, chunk = blockIdx.x & 7;
  int b = head >> 4, h = head & 15;
  int t = threadIdx.x, lane = t & 63, wave = t >> 6;
  int lp = t & 31, g8 = (t >> 5) << 3;
  size_t rowbase = (size_t)b * L_ + (size_t)chunk * 512;
  const f16* Kb = Kh + rowbase * D_ + h * DH;
  const f16* Vb = Vh + rowbase * D_ + h * DH;

  const int fm = lane & 15, fk = (lane >> 4) << 3;
  const int wm2 = (wave & 1) * 2;
  const int wn4 = (wave >> 1) * 4;
  f32x4 acc[2][4] = {};

  for (int l0 = 0; l0 < 512; l0 += 64) {
    __syncthreads();
    {
      const f16* r0 = Kb + (size_t)(l0 + 2*lp) * D_ + g8;
      f16x8 a0 = *(const f16x8*)r0;
      f16x8 a1 = *(const f16x8*)(r0 + D_);
#pragma unroll
      for (int j = 0; j < 8; ++j) {
        union { f16 h2[2]; uint32_t u; } pk;
        pk.h2[0] = a0[j]; pk.h2[1] = a1[j];
        *(uint32_t*)&sKt[(g8 + j) * SKT + 2*lp] = pk.u;
      }
      const f16* v0p = Vb + (size_t)(l0 + 2*lp) * D_ + g8;
      f16x8 b0 = *(const f16x8*)v0p;
      f16x8 b1 = *(const f16x8*)(v0p + D_);
#pragma unroll
      for (int j = 0; j < 8; ++j) {
        float x0 = (float)b0[j], x1 = (float)b1[j];
        union { f16 h2[2]; uint32_t u; } pp, pm;
        pp.h2[0] = (f16)fmaxf(x0, 0.f); pp.h2[1] = (f16)fmaxf(x1, 0.f);
        pm.h2[0] = (f16)fminf(x0, 0.f); pm.h2[1] = (f16)fminf(x1, 0.f);
        *(uint32_t*)&sVt[(g8 + j) * SKT + 2*lp]        = pp.u;
        *(uint32_t*)&sVt[(64 + g8 + j) * SKT + 2*lp]   = pm.u;
      }
    }
    __syncthreads();
#pragma unroll
    for (int ks = 0; ks < 2; ++ks) {
      f16x8 af[2], bf[4];
#pragma unroll
      for (int i = 0; i < 2; ++i)
        af[i] = *(const f16x8*)&sKt[((wm2+i)*16 + fm) * SKT + ks*32 + fk];
#pragma unroll
      for (int j = 0; j < 4; ++j)
        bf[j] = *(const f16x8*)&sVt[((wn4+j)*16 + fm) * SKT + ks*32 + fk];
#pragma unroll
      for (int i = 0; i < 2; ++i)
#pragma unroll
        for (int j = 0; j < 4; ++j)
          acc[i][j] = MFMA(af[i], bf[j], acc[i][j]);
    }
  }
  const int cr = (lane >> 4) << 2, ccol = lane & 15;
  float* pb = part + (size_t)(head * 8 + chunk) * 8192;
#pragma unroll
  for (int i = 0; i < 2; ++i)
#pragma unroll
    for (int j = 0; j < 4; ++j) {
      int d = (wm2 + i) * 16 + cr;
      int c2 = (wn4 + j) * 16 + ccol;
#pragma unroll
      for (int r = 0; r < 4; ++r)
        pb[(d + r) * 128 + c2] = acc[i][j][r];
    }
}

// ---------------- fused reduce-over-chunks + transpose + f16 cvt -----------
__global__ __launch_bounds__(256) void k_kv_redcvt(const float* __restrict__ part,
                                                   f16* __restrict__ kvh) {
  int head = blockIdx.x, t = threadIdx.x;
  int c = t >> 1, half = t & 1;
  const float* src = part + (size_t)head * 8 * 8192 + half * 32 * 128 + c;
  f16* dst = kvh + (size_t)head * 8192 + c * 64 + half * 32;
  f16 buf[32];
#pragma unroll
  for (int kk = 0; kk < 32; ++kk) {
    float s = 0.f;
#pragma unroll
    for (int ch = 0; ch < 8; ++ch) s += src[(size_t)ch * 8192 + kk * 128];
    buf[kk] = (f16)s;
  }
#pragma unroll
  for (int q = 0; q < 4; ++q) ((f16x8*)dst)[q] = *(const f16x8*)&buf[q * 8];
}

// ---------------- heads via MFMA: o = l2n(Q@kv+) + l2n(Q@kv-) --------------
// fp32 output (feeds fp32-A O-GEMM); LDS-staged coalesced 256B stores.
#define SH 72
__global__ __launch_bounds__(256) void k_heads_mfma(const f16* __restrict__ Qh,
                                                    const f16* __restrict__ kvh,
                                                    float* __restrict__ O) {
  __shared__ __align__(16) char hsmem[2 * 128 * SH * 2];  // 36864 B
  f16* sQ  = (f16*)hsmem;
  f16* sKV = (f16*)(hsmem + 128 * SH * 2);
  int bi = blockIdx.x;
  int head = bi >> 5, mt = bi & 31;
  int b = head >> 4, h = head & 15;
  int t = threadIdx.x, lane = t & 63, wave = t >> 6;
  size_t qbase = ((size_t)(b * L_ + mt * 128)) * D_ + h * DH;
  const f16* kvp = kvh + (size_t)head * 8192;
#pragma unroll
  for (int p = 0; p < 4; ++p) {
    int c = p * 256 + t;
    int row = c >> 3, off = (c & 7) * 8;
    f16x8 q = *(const f16x8*)(Qh + qbase + (size_t)row * D_ + off);
    *(f16x8*)&sQ[row * SH + off] = q;
    f16x8 kv8 = *(const f16x8*)(kvp + row * 64 + off);
    *(f16x8*)&sKV[row * SH + off] = kv8;
  }
  __syncthreads();

  const int fm = lane & 15, fk = (lane >> 4) << 3;
  const int wm = wave * 32;
  f32x4 acc[2][8] = {};
#pragma unroll
  for (int ks = 0; ks < 2; ++ks) {
    f16x8 a0 = *(const f16x8*)&sQ[(wm + fm) * SH + ks * 32 + fk];
    f16x8 a1 = *(const f16x8*)&sQ[(wm + 16 + fm) * SH + ks * 32 + fk];
#pragma unroll
    for (int j = 0; j < 8; ++j) {
      f16x8 bj = *(const f16x8*)&sKV[(j * 16 + fm) * SH + ks * 32 + fk];
      acc[0][j] = MFMA(a0, bj, acc[0][j]);
      acc[1][j] = MFMA(a1, bj, acc[1][j]);
    }
  }
  __syncthreads();   // all LDS frag reads done before overwriting as sOf
  float* sOf = (float*)hsmem;   // [128][68]: +4 rows -> +16 banks
  const int cr = (lane >> 4) << 2, ccol = lane & 15;
#pragma unroll
  for (int i = 0; i < 2; ++i)
#pragma unroll
    for (int r = 0; r < 4; ++r) {
      int row = wm + i * 16 + cr + r;
      float sp = 0.f, sm = 0.f;
#pragma unroll
      for (int j = 0; j < 4; ++j) {
        sp += acc[i][j][r] * acc[i][j][r];
        sm += acc[i][j + 4][r] * acc[i][j + 4][r];
      }
      sp += __shfl_xor(sp, 1, 64); sm += __shfl_xor(sm, 1, 64);
      sp += __shfl_xor(sp, 2, 64); sm += __shfl_xor(sm, 2, 64);
      sp += __shfl_xor(sp, 4, 64); sm += __shfl_xor(sm, 4, 64);
      sp += __shfl_xor(sp, 8, 64); sm += __shfl_xor(sm, 8, 64);
      float rp = 1.0f / fmaxf(sqrtf(sp), 1e-12f);
      float rm = 1.0f / fmaxf(sqrtf(sm), 1e-12f);
#pragma unroll
      for (int j = 0; j < 4; ++j)
        sOf[row * 68 + j * 16 + ccol] = acc[i][j][r] * rp + acc[i][j + 4][r] * rm;
    }
  __syncthreads();
#pragma unroll
  for (int sp = 0; sp < 8; ++sp) {
    int rl = sp * 16 + (t >> 4);
    int c4 = (t & 15) * 4;
    f32x4 v = *(const f32x4*)&sOf[rl * 68 + c4];
    *(f32x4*)&O[qbase + (size_t)rl * D_ + c4] = v;
  }
}

// ---------------- launch ----------------
extern "C" void kernel_launch(void* const* d_in, const int* in_sizes, int n_in,
                              void* d_out, int out_size, void* d_ws, size_t ws_size,
                              hipStream_t stream) {
  const float* queries = (const float*)d_in[0];
  const float* values  = (const float*)d_in[1];
  const float* keys    = (const float*)d_in[2];
  const float* mask    = (const float*)d_in[3];
  const float* Wq = (const float*)d_in[4];  const float* bq = (const float*)d_in[5];
  const float* Wk = (const float*)d_in[6];  const float* bk = (const float*)d_in[7];
  const float* Wv = (const float*)d_in[8];  const float* bv = (const float*)d_in[9];
  const float* Wo = (const float*)d_in[10]; const float* bo = (const float*)d_in[11];
  float* out = (float*)d_out;

  const size_t MB = 1024ull * 1024ull;
  const size_t NEED = 126 * MB;
  if (ws_size < NEED) return;

  char* ws = (char*)d_ws;
  const size_t DD = (size_t)D_ * D_;
  f16*   Wqh  = (f16*)(ws);                 // 2MB
  f16*   Wkh  = (f16*)(ws + 2 * MB);        // 2MB
  f16*   Wcv  = (f16*)(ws + 4 * MB);        // 4MB interleaved [hi;lo] V weight
  f16*   Wco  = (f16*)(ws + 8 * MB);        // 4MB interleaved [hi;lo] O weight
  f16*   Qh   = (f16*)(ws + 12 * MB);       // 32MB (Q projection f16)
  f16*   kp   = (f16*)(ws + 44 * MB);       // 32MB (K proj, sig+l2n+mask)
  f16*   vp   = (f16*)(ws + 76 * MB);       // 32MB (V proj f16)
  float* part = (float*)(ws + 108 * MB);    // 16MB
  f16*   kvh  = (f16*)(ws + 124 * MB);      // 1MB
  // heads fp32 output overlays kp+vp (both dead after k_kv_mfma): 64MB
  float* Ao   = (float*)(ws + 44 * MB);

  const int DD8 = (int)(DD / 8);            // 131072
  const int DD4 = (int)(DD / 4);            // 262144

  // weight prep (2 launches)
  k_cvt2 <<<2 * DD8 / 256, 256, 0, stream>>>(Wq, Wqh, Wk, Wkh, DD8);
  k_split2<<<2 * DD4 / 256, 256, 0, stream>>>(Wv, Wcv, Wo, Wco, DD4);

  // combined Q|K GEMM (fp32 A direct; 512 blocks, 2 jobs)
  {
    GemmJob jq = { queries, Wqh, bq, nullptr, nullptr, Qh, 1, 1024 };
    GemmJob jk = { keys,    Wkh, bk, mask,    nullptr, kp, 1, 1024 };
    k_gemm8<<<512, 512, 0, stream>>>(jq, jk, 256, M_, 1024);
  }

  // V GEMM (fp32 A direct, weight-split fold, f16 out)
  {
    GemmJob jv = { values, Wcv, bv, nullptr, nullptr, vp, 2, 2048 };
    k_gemm8<<<512, 512, 0, stream>>>(jv, jv, 512, M_, 1024);
  }

  k_kv_mfma<<<64 * 8, 256, 0, stream>>>(kp, vp, part);
  k_kv_redcvt<<<64, 256, 0, stream>>>(part, kvh);
  k_heads_mfma<<<64 * 32, 256, 0, stream>>>(Qh, kvh, Ao);

  // O GEMM (fp32 A = heads output)
  {
    GemmJob jo = { Ao, Wco, bo, nullptr, out, nullptr, 3, 2048 };
    k_gemm8<<<512, 512, 0, stream>>>(jo, jo, 512, M_, 1024);
  }
}

// Round 5
// 496.797 us; speedup vs baseline: 1.3370x; 1.3370x over previous
//
#include <hip/hip_runtime.h>
#include <stdint.h>

// Problem dims (fixed)
#define B_  4
#define L_  4096
#define D_  1024
#define H_  16
#define DH  64
#define M_  (B_*L_)   // 16384 rows

typedef _Float16 f16;
typedef __attribute__((ext_vector_type(8))) _Float16 f16x8;
typedef __attribute__((ext_vector_type(4))) _Float16 f16x4;
typedef __attribute__((ext_vector_type(4))) float    f32x4;

// ---------------- async global->LDS (16B per lane) ----------------
__device__ __forceinline__ void cp16(const void* g, void* l) {
  __builtin_amdgcn_global_load_lds(
      (const __attribute__((address_space(1))) void*)g,
      (__attribute__((address_space(3))) void*)l,
      16, 0, 0);
}

#define MFMA(a,b,c) __builtin_amdgcn_mfma_f32_16x16x32_f16(a,b,c,0,0,0)

// 8-phase sync primitives (T3+T4+T5).
#define PH_IN do { __builtin_amdgcn_s_barrier(); \
  asm volatile("s_waitcnt lgkmcnt(0)" ::: "memory"); \
  __builtin_amdgcn_sched_barrier(0); \
  __builtin_amdgcn_s_setprio(1); } while (0)
#define PH_OUT do { __builtin_amdgcn_s_setprio(0); \
  __builtin_amdgcn_sched_barrier(0); \
  asm volatile("" ::: "memory"); \
  __builtin_amdgcn_s_barrier(); } while (0)
#define PH_OUT_VM(nimm) do { __builtin_amdgcn_s_setprio(0); \
  __builtin_amdgcn_sched_barrier(0); \
  asm volatile("s_waitcnt vmcnt(" #nimm ")" ::: "memory"); \
  __builtin_amdgcn_s_barrier(); } while (0)

// ---------------- cast / split helpers ----------------
__device__ __forceinline__ void cvt8_one(const float* __restrict__ x,
                                         f16* __restrict__ y, int i) {
  const float4* xv = (const float4*)x;
  float4 a = xv[2*i], b = xv[2*i+1];
  f16x8 o;
  o[0]=(f16)a.x; o[1]=(f16)a.y; o[2]=(f16)a.z; o[3]=(f16)a.w;
  o[4]=(f16)b.x; o[5]=(f16)b.y; o[6]=(f16)b.z; o[7]=(f16)b.w;
  ((f16x8*)y)[i] = o;
}

// W row n: hi -> cat row 32*(n>>4)+(n&15), lo -> +16.
__device__ __forceinline__ void split_one(const float* __restrict__ x,
                                          f16* __restrict__ cat, int i) {
  float4 a = ((const float4*)x)[i];
  int n  = i >> 8;
  int k4 = i & 255;
  f16 h0=(f16)a.x, h1=(f16)a.y, h2=(f16)a.z, h3=(f16)a.w;
  f16x4 hv = {h0, h1, h2, h3};
  f16x4 lv = {(f16)(a.x-(float)h0), (f16)(a.y-(float)h1),
              (f16)(a.z-(float)h2), (f16)(a.w-(float)h3)};
  size_t rh = (size_t)((n >> 4) * 32 + (n & 15));
  ((f16x4*)cat)[rh * 256 + k4]        = hv;
  ((f16x4*)cat)[(rh + 16) * 256 + k4] = lv;
}

// single fp32->f16 cast kernel (values)
__global__ __launch_bounds__(256) void k_cvt_f16(const float* __restrict__ x,
                                                 f16* __restrict__ y, int n8) {
  int i = blockIdx.x * 256 + threadIdx.x;
  if (i >= n8) return;
  cvt8_one(x, y, i);
}

// merged prep: weights hi-cvt (Wq,Wk) + weight-split (Wv,Wo) + q/k input cast.
// grid ranges: [0,1024) wcvt, [1024,3072) wsplit, [3072,19456) qk cast.
__global__ __launch_bounds__(256) void k_prep(
    const float* __restrict__ Wq, f16* __restrict__ Wqh,
    const float* __restrict__ Wk, f16* __restrict__ Wkh,
    const float* __restrict__ Wv, f16* __restrict__ Wcv,
    const float* __restrict__ Wo, f16* __restrict__ Wco,
    const float* __restrict__ q32, f16* __restrict__ q16,
    const float* __restrict__ k32, f16* __restrict__ k16) {
  const int DD8 = 131072, DD4 = 262144, n8 = 2097152;
  int bid = blockIdx.x, t = threadIdx.x;
  if (bid < 1024) {
    int i = bid * 256 + t;
    if (i < DD8) cvt8_one(Wq, Wqh, i);
    else         cvt8_one(Wk, Wkh, i - DD8);
  } else if (bid < 3072) {
    int i = (bid - 1024) * 256 + t;
    if (i < DD4) split_one(Wv, Wcv, i);
    else         split_one(Wo, Wco, i - DD4);
  } else {
    int i = (bid - 3072) * 256 + t;
    if (i < n8) cvt8_one(q32, q16, i);
    else        cvt8_one(k32, k16, i - n8);
  }
}

// ---------------- 256x256 8-phase GEMM (T1+T2+T3+T4+T5) --------------------
// 512 thr = 8 waves (2M x 4N); wave tile 128x64; BK=64, dbuf 128KB LDS,
// swizzle blk^=(row&7) on 16B chunks. All epilogues stage fp32 into LDS and
// emit coalesced wide stores; mode-1 does sigmoid+l2norm on the READBACK side.
// __launch_bounds__(512,2): cap 256 unified regs/wave (VGPR128+AGPR128 = acc
// budget exactly) -- (512,1) regressed V/O dispatches ~60us total [R3].
// mode 1: bias+sigmoid+l2norm(64-col head)+opt mask -> f16 (N=1024)
// mode 2: fold hi/lo pairs + bias -> f16   (N=2048 interleaved -> 1024)
// mode 3: fold hi/lo pairs + bias -> fp32  (N=2048 interleaved -> 1024)
struct GemmJob {
  const f16* A; const f16* Bw; const float* bias; const float* mask;
  float* Cf; f16* Ch; int mode; int N;
};

__global__ __launch_bounds__(512, 2) void k_gemm8(GemmJob j0, GemmJob j1,
                                                  int nblk0, int M, int K) {
  // 131072 K-loop dbuf; mode1 staging [128][260]=133120; mode2/3 [256][132]=135168
  __shared__ __align__(16) char smem[135168];
  char* sA = smem;
  char* sB = smem + 65536;
  const int t = threadIdx.x;

  int raw = (int)blockIdx.x;
  GemmJob J; int bid, nblk;
  if (raw < nblk0) { J = j0; bid = raw;         nblk = nblk0; }
  else             { J = j1; bid = raw - nblk0; nblk = (int)gridDim.x - nblk0; }
  const int N = J.N;
  const int nbn = N >> 8;
  { // XCD-aware swizzle within job (job sizes are multiples of 8)
    int cpx = nblk >> 3;
    bid = (bid & 7) * cpx + (bid >> 3);
  }
  const int bm = (bid / nbn) << 8;
  const int bn = (bid % nbn) << 8;
  const int lane = t & 63, wave = t >> 6;
  const int wm = wave >> 2;        // 0..1 : rows [wm*128, +128)
  const int wn = wave & 3;         // 0..3 : cols [wn*64, +64)
  const int fm = lane & 15, fkb = lane >> 4;

  const f16* Ab = J.A;
  const f16* Bb = J.Bw;
  auto SA_ = [&](int T, int buf, int half) {
#pragma unroll
    for (int q = 0; q < 2; ++q) {
      int li = (q << 9) + t;
      int row = li >> 3, cb = li & 7;
      const f16* g = Ab + (size_t)(bm + (half << 7) + row) * K
                        + (T << 6) + ((cb ^ (row & 7)) << 3);
      cp16(g, sA + buf * 32768 + half * 16384 + li * 16);
    }
  };
  auto SB_ = [&](int T, int buf, int half) {
#pragma unroll
    for (int q = 0; q < 2; ++q) {
      int li = (q << 9) + t;
      int row = li >> 3, cb = li & 7;
      const f16* g = Bb + (size_t)(bn + (half << 7) + row) * K
                        + (T << 6) + ((cb ^ (row & 7)) << 3);
      cp16(g, sB + buf * 32768 + half * 16384 + li * 16);
    }
  };
  auto LDA = [&](int buf, int i, int ks) -> f16x8 {
    int row = (i << 4) + fm;
    int blk = ((ks << 2) + fkb) ^ (row & 7);
    return *(const f16x8*)(sA + buf * 32768 + (wm << 14) + (row << 7) + (blk << 4));
  };
  auto LDB = [&](int buf, int j, int ks) -> f16x8 {
    int row = ((wn & 1) << 6) + (j << 4) + fm;
    int blk = ((ks << 2) + fkb) ^ (row & 7);
    return *(const f16x8*)(sB + buf * 32768 + ((wn >> 1) << 14) + (row << 7) + (blk << 4));
  };

  f32x4 acc[8][4] = {};

  // ---- prologue
  SA_(0, 0, 0); SA_(0, 0, 1);
  SB_(0, 0, 0); SB_(0, 0, 1);
  SB_(1, 1, 0); SB_(1, 1, 1);
  asm volatile("s_waitcnt vmcnt(4)" ::: "memory");
  __builtin_amdgcn_s_barrier();

  const int NI = K >> 7;
  for (int it = 0; it < NI; ++it) {
    const bool nl = (it != NI - 1);
    const int t2 = 2 * it + 2, t3 = 2 * it + 3;
    f16x8 aL[4][2], aH[4][2], bA[2][2], bB[2][2];

    // p1 (buf0): read aL,bA; stage b1.A h0
#pragma unroll
    for (int i = 0; i < 4; ++i) { aL[i][0] = LDA(0,i,0); aL[i][1] = LDA(0,i,1); }
#pragma unroll
    for (int j = 0; j < 2; ++j) { bA[j][0] = LDB(0,j,0); bA[j][1] = LDB(0,j,1); }
    SA_(2*it+1, 1, 0);
    PH_IN;
#pragma unroll
    for (int i = 0; i < 4; ++i)
#pragma unroll
      for (int j = 0; j < 2; ++j) {
        acc[i][j] = MFMA(aL[i][0], bA[j][0], acc[i][j]);
        acc[i][j] = MFMA(aL[i][1], bA[j][1], acc[i][j]);
      }
    PH_OUT;
    // p2: read bB; stage b1.A h1
#pragma unroll
    for (int j = 0; j < 2; ++j) { bB[j][0] = LDB(0,j+2,0); bB[j][1] = LDB(0,j+2,1); }
    SA_(2*it+1, 1, 1);
    PH_IN;
#pragma unroll
    for (int i = 0; i < 4; ++i)
#pragma unroll
      for (int j = 0; j < 2; ++j) {
        acc[i][j+2] = MFMA(aL[i][0], bB[j][0], acc[i][j+2]);
        acc[i][j+2] = MFMA(aL[i][1], bB[j][1], acc[i][j+2]);
      }
    PH_OUT;
    // p3: read aH; stage b0.B h0
#pragma unroll
    for (int i = 0; i < 4; ++i) { aH[i][0] = LDA(0,i+4,0); aH[i][1] = LDA(0,i+4,1); }
    if (nl) SB_(t2, 0, 0);
    PH_IN;
#pragma unroll
    for (int i = 0; i < 4; ++i)
#pragma unroll
      for (int j = 0; j < 2; ++j) {
        acc[i+4][j] = MFMA(aH[i][0], bA[j][0], acc[i+4][j]);
        acc[i+4][j] = MFMA(aH[i][1], bA[j][1], acc[i+4][j]);
      }
    PH_OUT;
    // p4: stage b0.B h1; vmcnt -> b1 landed
    if (nl) SB_(t2, 0, 1);
    PH_IN;
#pragma unroll
    for (int i = 0; i < 4; ++i)
#pragma unroll
      for (int j = 0; j < 2; ++j) {
        acc[i+4][j+2] = MFMA(aH[i][0], bB[j][0], acc[i+4][j+2]);
        acc[i+4][j+2] = MFMA(aH[i][1], bB[j][1], acc[i+4][j+2]);
      }
    if (nl) PH_OUT_VM(4); else PH_OUT_VM(0);
    // p5 (buf1)
#pragma unroll
    for (int i = 0; i < 4; ++i) { aL[i][0] = LDA(1,i,0); aL[i][1] = LDA(1,i,1); }
#pragma unroll
    for (int j = 0; j < 2; ++j) { bA[j][0] = LDB(1,j,0); bA[j][1] = LDB(1,j,1); }
    if (nl) SA_(t2, 0, 0);
    PH_IN;
#pragma unroll
    for (int i = 0; i < 4; ++i)
#pragma unroll
      for (int j = 0; j < 2; ++j) {
        acc[i][j] = MFMA(aL[i][0], bA[j][0], acc[i][j]);
        acc[i][j] = MFMA(aL[i][1], bA[j][1], acc[i][j]);
      }
    PH_OUT;
    // p6
#pragma unroll
    for (int j = 0; j < 2; ++j) { bB[j][0] = LDB(1,j+2,0); bB[j][1] = LDB(1,j+2,1); }
    if (nl) SA_(t2, 0, 1);
    PH_IN;
#pragma unroll
    for (int i = 0; i < 4; ++i)
#pragma unroll
      for (int j = 0; j < 2; ++j) {
        acc[i][j+2] = MFMA(aL[i][0], bB[j][0], acc[i][j+2]);
        acc[i][j+2] = MFMA(aL[i][1], bB[j][1], acc[i][j+2]);
      }
    PH_OUT;
    // p7
#pragma unroll
    for (int i = 0; i < 4; ++i) { aH[i][0] = LDA(1,i+4,0); aH[i][1] = LDA(1,i+4,1); }
    if (nl) SB_(t3, 1, 0);
    PH_IN;
#pragma unroll
    for (int i = 0; i < 4; ++i)
#pragma unroll
      for (int j = 0; j < 2; ++j) {
        acc[i+4][j] = MFMA(aH[i][0], bA[j][0], acc[i+4][j]);
        acc[i+4][j] = MFMA(aH[i][1], bA[j][1], acc[i+4][j]);
      }
    PH_OUT;
    // p8: stage b1.B h1; vmcnt -> b0 landed
    if (nl) SB_(t3, 1, 1);
    PH_IN;
#pragma unroll
    for (int i = 0; i < 4; ++i)
#pragma unroll
      for (int j = 0; j < 2; ++j) {
        acc[i+4][j+2] = MFMA(aH[i][0], bB[j][0], acc[i+4][j+2]);
        acc[i+4][j+2] = MFMA(aH[i][1], bB[j][1], acc[i+4][j+2]);
      }
    PH_OUT_VM(4);
  }

  // ---------------- epilogue (LDS-coalesced stores) ----------------
  // C/D layout: col = lane&15, row = (lane>>4)*4 + reg  [m89/m91]
  const int cr = (lane >> 4) << 2, ccol = lane & 15;
  float* sOut = (float*)smem;
  if (J.mode == 1) {
    // Stage RAW acc+bias fp32 into sOut[128][260] per 128-row half; all
    // sigmoid/l2norm math happens on readback with all 512 threads.
    float bvj[4];
#pragma unroll
    for (int j = 0; j < 4; ++j) bvj[j] = J.bias[bn + wn*64 + j*16 + ccol];
    const int rbr = t >> 6;            // readback row-within-group (wave id)
    const int c4  = (t & 63) * 4;      // readback col (4 f32)
    for (int h = 0; h < 2; ++h) {
      if (wm == h) {
#pragma unroll
        for (int i = 0; i < 8; ++i)
#pragma unroll
          for (int r = 0; r < 4; ++r) {
            int rl = i*16 + cr + r;    // 0..127 within this half
#pragma unroll
            for (int j = 0; j < 4; ++j)
              sOut[rl*260 + wn*64 + j*16 + ccol] = acc[i][j][r] + bvj[j];
          }
      }
      __syncthreads();
      // readback: per row, each 16-lane group owns one 64-col head;
      // 4-deep shfl_xor over the group gives the head's sum.
#pragma unroll
      for (int sp = 0; sp < 16; ++sp) {
        int rr = sp*8 + rbr;
        int gm = bm + h*128 + rr;
        f32x4 v = *(const f32x4*)&sOut[rr*260 + c4];
        float s0 = 1.0f / (1.0f + __expf(-v[0]));
        float s1 = 1.0f / (1.0f + __expf(-v[1]));
        float s2 = 1.0f / (1.0f + __expf(-v[2]));
        float s3 = 1.0f / (1.0f + __expf(-v[3]));
        float ss = s0*s0 + s1*s1 + s2*s2 + s3*s3;
        ss += __shfl_xor(ss, 1, 64);
        ss += __shfl_xor(ss, 2, 64);
        ss += __shfl_xor(ss, 4, 64);
        ss += __shfl_xor(ss, 8, 64);
        float sc = 1.0f / fmaxf(sqrtf(ss), 1e-12f);
        if (J.mask) sc *= J.mask[gm];
        f16x4 o = {(f16)(s0*sc), (f16)(s1*sc), (f16)(s2*sc), (f16)(s3*sc)};
        *(f16x4*)&J.Ch[(size_t)gm * N + bn + c4] = o;
      }
      __syncthreads();
    }
  } else {
    // fold hi/lo, stage into sOut[256][132] (pitch 132: +4 rows -> +16 banks)
#pragma unroll
    for (int j2 = 0; j2 < 2; ++j2) {
      int ocl = wn*32 + j2*16 + ccol;       // 0..127 block-local real col
      float bv = J.bias[(bn >> 1) + ocl];
#pragma unroll
      for (int i = 0; i < 8; ++i)
#pragma unroll
        for (int r = 0; r < 4; ++r) {
          int rl = wm*128 + i*16 + cr + r;  // 0..255
          sOut[rl*132 + ocl] = acc[i][2*j2][r] + acc[i][2*j2+1][r] + bv;
        }
    }
    __syncthreads();
    const int No = N >> 1;                  // 1024
#pragma unroll
    for (int sp = 0; sp < 16; ++sp) {
      int rl = sp*16 + (t >> 5);
      int c4 = (t & 31) * 4;
      f32x4 v = *(const f32x4*)&sOut[rl*132 + c4];
      size_t g = (size_t)(bm + rl) * No + (bn >> 1) + c4;
      if (J.mode == 2) {
        f16x4 o = {(f16)v[0], (f16)v[1], (f16)v[2], (f16)v[3]};
        *(f16x4*)&J.Ch[g] = o;
      } else {
        *(f32x4*)&J.Cf[g] = v;
      }
    }
  }
}

// ---------------- kv via MFMA: per (head, chunk of 512 rows) ---------------
#define SKT 72
__global__ __launch_bounds__(256) void k_kv_mfma(const f16* __restrict__ Kh,
                                                 const f16* __restrict__ Vh,
                                                 float* __restrict__ part) {
  __shared__ __align__(16) f16 sKt[64 * SKT];    // [d][l]
  __shared__ __align__(16) f16 sVt[128 * SKT];   // [c2][l]
  int head = blockIdx.x >> 3, chunk = blockIdx.x & 7;
  int b = head >> 4, h = head & 15;
  int t = threadIdx.x, lane = t & 63, wave = t >> 6;
  int lp = t & 31, g8 = (t >> 5) << 3;
  size_t rowbase = (size_t)b * L_ + (size_t)chunk * 512;
  const f16* Kb = Kh + rowbase * D_ + h * DH;
  const f16* Vb = Vh + rowbase * D_ + h * DH;

  const int fm = lane & 15, fk = (lane >> 4) << 3;
  const int wm2 = (wave & 1) * 2;
  const int wn4 = (wave >> 1) * 4;
  f32x4 acc[2][4] = {};

  for (int l0 = 0; l0 < 512; l0 += 64) {
    __syncthreads();
    {
      const f16* r0 = Kb + (size_t)(l0 + 2*lp) * D_ + g8;
      f16x8 a0 = *(const f16x8*)r0;
      f16x8 a1 = *(const f16x8*)(r0 + D_);
#pragma unroll
      for (int j = 0; j < 8; ++j) {
        union { f16 h2[2]; uint32_t u; } pk;
        pk.h2[0] = a0[j]; pk.h2[1] = a1[j];
        *(uint32_t*)&sKt[(g8 + j) * SKT + 2*lp] = pk.u;
      }
      const f16* v0p = Vb + (size_t)(l0 + 2*lp) * D_ + g8;
      f16x8 b0 = *(const f16x8*)v0p;
      f16x8 b1 = *(const f16x8*)(v0p + D_);
#pragma unroll
      for (int j = 0; j < 8; ++j) {
        float x0 = (float)b0[j], x1 = (float)b1[j];
        union { f16 h2[2]; uint32_t u; } pp, pm;
        pp.h2[0] = (f16)fmaxf(x0, 0.f); pp.h2[1] = (f16)fmaxf(x1, 0.f);
        pm.h2[0] = (f16)fminf(x0, 0.f); pm.h2[1] = (f16)fminf(x1, 0.f);
        *(uint32_t*)&sVt[(g8 + j) * SKT + 2*lp]        = pp.u;
        *(uint32_t*)&sVt[(64 + g8 + j) * SKT + 2*lp]   = pm.u;
      }
    }
    __syncthreads();
#pragma unroll
    for (int ks = 0; ks < 2; ++ks) {
      f16x8 af[2], bf[4];
#pragma unroll
      for (int i = 0; i < 2; ++i)
        af[i] = *(const f16x8*)&sKt[((wm2+i)*16 + fm) * SKT + ks*32 + fk];
#pragma unroll
      for (int j = 0; j < 4; ++j)
        bf[j] = *(const f16x8*)&sVt[((wn4+j)*16 + fm) * SKT + ks*32 + fk];
#pragma unroll
      for (int i = 0; i < 2; ++i)
#pragma unroll
        for (int j = 0; j < 4; ++j)
          acc[i][j] = MFMA(af[i], bf[j], acc[i][j]);
    }
  }
  const int cr = (lane >> 4) << 2, ccol = lane & 15;
  float* pb = part + (size_t)(head * 8 + chunk) * 8192;
#pragma unroll
  for (int i = 0; i < 2; ++i)
#pragma unroll
    for (int j = 0; j < 4; ++j) {
      int d = (wm2 + i) * 16 + cr;
      int c2 = (wn4 + j) * 16 + ccol;
#pragma unroll
      for (int r = 0; r < 4; ++r)
        pb[(d + r) * 128 + c2] = acc[i][j][r];
    }
}

// ---------------- fused reduce-over-chunks + transpose + f16 cvt -----------
__global__ __launch_bounds__(256) void k_kv_redcvt(const float* __restrict__ part,
                                                   f16* __restrict__ kvh) {
  int head = blockIdx.x, t = threadIdx.x;
  int c = t >> 1, half = t & 1;
  const float* src = part + (size_t)head * 8 * 8192 + half * 32 * 128 + c;
  f16* dst = kvh + (size_t)head * 8192 + c * 64 + half * 32;
  f16 buf[32];
#pragma unroll
  for (int kk = 0; kk < 32; ++kk) {
    float s = 0.f;
#pragma unroll
    for (int ch = 0; ch < 8; ++ch) s += src[(size_t)ch * 8192 + kk * 128];
    buf[kk] = (f16)s;
  }
#pragma unroll
  for (int q = 0; q < 4; ++q) ((f16x8*)dst)[q] = *(const f16x8*)&buf[q * 8];
}

// ---------------- heads via MFMA: o = l2n(Q@kv+) + l2n(Q@kv-) --------------
// Epilogue stages fp32 into LDS (union with sQ/sKV) -> coalesced 128B f16 rows.
#define SH 72
__global__ __launch_bounds__(256) void k_heads_mfma(const f16* __restrict__ Qh,
                                                    const f16* __restrict__ kvh,
                                                    f16* __restrict__ O) {
  __shared__ __align__(16) char hsmem[2 * 128 * SH * 2];  // 36864 B
  f16* sQ  = (f16*)hsmem;
  f16* sKV = (f16*)(hsmem + 128 * SH * 2);
  int bi = blockIdx.x;
  int head = bi >> 5, mt = bi & 31;
  int b = head >> 4, h = head & 15;
  int t = threadIdx.x, lane = t & 63, wave = t >> 6;
  size_t qbase = ((size_t)(b * L_ + mt * 128)) * D_ + h * DH;
  const f16* kvp = kvh + (size_t)head * 8192;
#pragma unroll
  for (int p = 0; p < 4; ++p) {
    int c = p * 256 + t;
    int row = c >> 3, off = (c & 7) * 8;
    f16x8 q = *(const f16x8*)(Qh + qbase + (size_t)row * D_ + off);
    *(f16x8*)&sQ[row * SH + off] = q;
    f16x8 kv8 = *(const f16x8*)(kvp + row * 64 + off);
    *(f16x8*)&sKV[row * SH + off] = kv8;
  }
  __syncthreads();

  const int fm = lane & 15, fk = (lane >> 4) << 3;
  const int wm = wave * 32;
  f32x4 acc[2][8] = {};
#pragma unroll
  for (int ks = 0; ks < 2; ++ks) {
    f16x8 a0 = *(const f16x8*)&sQ[(wm + fm) * SH + ks * 32 + fk];
    f16x8 a1 = *(const f16x8*)&sQ[(wm + 16 + fm) * SH + ks * 32 + fk];
#pragma unroll
    for (int j = 0; j < 8; ++j) {
      f16x8 bj = *(const f16x8*)&sKV[(j * 16 + fm) * SH + ks * 32 + fk];
      acc[0][j] = MFMA(a0, bj, acc[0][j]);
      acc[1][j] = MFMA(a1, bj, acc[1][j]);
    }
  }
  __syncthreads();   // all LDS frag reads done before overwriting as sOf
  float* sOf = (float*)hsmem;   // [128][68]: +4 rows -> +16 banks
  const int cr = (lane >> 4) << 2, ccol = lane & 15;
#pragma unroll
  for (int i = 0; i < 2; ++i)
#pragma unroll
    for (int r = 0; r < 4; ++r) {
      int row = wm + i * 16 + cr + r;
      float sp = 0.f, sm = 0.f;
#pragma unroll
      for (int j = 0; j < 4; ++j) {
        sp += acc[i][j][r] * acc[i][j][r];
        sm += acc[i][j + 4][r] * acc[i][j + 4][r];
      }
      sp += __shfl_xor(sp, 1, 64); sm += __shfl_xor(sm, 1, 64);
      sp += __shfl_xor(sp, 2, 64); sm += __shfl_xor(sm, 2, 64);
      sp += __shfl_xor(sp, 4, 64); sm += __shfl_xor(sm, 4, 64);
      sp += __shfl_xor(sp, 8, 64); sm += __shfl_xor(sm, 8, 64);
      float rp = 1.0f / fmaxf(sqrtf(sp), 1e-12f);
      float rm = 1.0f / fmaxf(sqrtf(sm), 1e-12f);
#pragma unroll
      for (int j = 0; j < 4; ++j)
        sOf[row * 68 + j * 16 + ccol] = acc[i][j][r] * rp + acc[i][j + 4][r] * rm;
    }
  __syncthreads();
#pragma unroll
  for (int sp = 0; sp < 8; ++sp) {
    int rl = sp * 16 + (t >> 4);
    int c4 = (t & 15) * 4;
    f32x4 v = *(const f32x4*)&sOf[rl * 68 + c4];
    f16x4 o = {(f16)v[0], (f16)v[1], (f16)v[2], (f16)v[3]};
    *(f16x4*)&O[qbase + (size_t)rl * D_ + c4] = o;
  }
}

// ---------------- launch ----------------
extern "C" void kernel_launch(void* const* d_in, const int* in_sizes, int n_in,
                              void* d_out, int out_size, void* d_ws, size_t ws_size,
                              hipStream_t stream) {
  const float* queries = (const float*)d_in[0];
  const float* values  = (const float*)d_in[1];
  const float* keys    = (const float*)d_in[2];
  const float* mask    = (const float*)d_in[3];
  const float* Wq = (const float*)d_in[4];  const float* bq = (const float*)d_in[5];
  const float* Wk = (const float*)d_in[6];  const float* bk = (const float*)d_in[7];
  const float* Wv = (const float*)d_in[8];  const float* bv = (const float*)d_in[9];
  const float* Wo = (const float*)d_in[10]; const float* bo = (const float*)d_in[11];
  float* out = (float*)d_out;

  const size_t MB = 1024ull * 1024ull;
  const size_t NEED = 160 * MB;
  if (ws_size < NEED) return;

  char* ws = (char*)d_ws;
  const size_t DD = (size_t)D_ * D_;
  f16*   Wqh  = (f16*)(ws);                 // 2MB
  f16*   Wkh  = (f16*)(ws + 2 * MB);        // 2MB
  f16*   Wcv  = (f16*)(ws + 4 * MB);        // 4MB interleaved [hi;lo] V weight
  f16*   Wco  = (f16*)(ws + 8 * MB);        // 4MB interleaved [hi;lo] O weight
  f16*   Ah   = (f16*)(ws + 12 * MB);       // 32MB (q16 / v16 / heads out)
  f16*   Qh   = (f16*)(ws + 44 * MB);       // 32MB
  f16*   kvh  = (f16*)(ws + 78 * MB);       // 1MB (+1MB pad)
  float* part = (float*)(ws + 80 * MB);     // 16MB
  f16*   kp   = (f16*)(ws + 96 * MB);       // 32MB
  f16*   vp   = (f16*)(ws + 128 * MB);      // 32MB (k16 before V-GEMM) -> 160MB

  const int n8  = M_ * D_ / 8;              // 2097152

  f16* q16 = Ah;
  f16* k16 = vp;    // vp region free until V-GEMM writes it (after QK-GEMM)
  f16* v16 = Ah;    // after QK-GEMM consumed q16

  // merged prep: weights cvt+split + q/k casts (one launch)
  k_prep<<<19456, 256, 0, stream>>>(Wq, Wqh, Wk, Wkh, Wv, Wcv, Wo, Wco,
                                    queries, q16, keys, k16);

  // combined Q|K GEMM (512 blocks, 2 jobs)
  {
    GemmJob jq = { q16, Wqh, bq, nullptr, nullptr, Qh, 1, 1024 };
    GemmJob jk = { k16, Wkh, bk, mask,    nullptr, kp, 1, 1024 };
    k_gemm8<<<512, 512, 0, stream>>>(jq, jk, 256, M_, 1024);
  }

  // cast values, V GEMM (weight-split fold, f16 out)
  k_cvt_f16<<<n8 / 256, 256, 0, stream>>>(values, v16, n8);
  {
    GemmJob jv = { v16, Wcv, bv, nullptr, nullptr, vp, 2, 2048 };
    k_gemm8<<<512, 512, 0, stream>>>(jv, jv, 512, M_, 1024);
  }

  k_kv_mfma<<<64 * 8, 256, 0, stream>>>(kp, vp, part);
  k_kv_redcvt<<<64, 256, 0, stream>>>(part, kvh);
  k_heads_mfma<<<64 * 32, 256, 0, stream>>>(Qh, kvh, Ah);

  {
    GemmJob jo = { Ah, Wco, bo, nullptr, out, nullptr, 3, 2048 };
    k_gemm8<<<512, 512, 0, stream>>>(jo, jo, 512, M_, 1024);
  }
}